// Round 6
// baseline (434.034 us; speedup 1.0000x reference)
//
#include <hip/hip_runtime.h>

// HMM forward scan. U=256, N=64, S=4, B=64, T=1024.
// R14: j-SPLIT ACROSS WAVE PAIRS -> 2 waves/SIMD.
// Evidence R8-R13: per-step period pinned ~730-780cy across 8/12/14-MFMA,
// chained/unchained, shfl/MFMA-ss variants; MfmaUtil 33% == exact phase
// serialization of V and M within ONE wave (1 wave/SIMD, 1024 waves fixed
// by the old decomposition). Fix: 8 waves/block (512 thr); wave parity
// p owns output states j in [32p,32p+32) = output tiles jt in {2p,2p+1}
// = K-half p of the b-operand. Per step each wave packs its half-fragment
// (identical packing code), exchanges via LDS (ds_write_b128 + barrier +
// ds_read_b128, double-buffered, ONE barrier/step), then 8 MFMAs:
//   Ev x2 (be, indep of exchange)     -> issued first
//   Pown x2 (own frag, in-register)   -> covers ds_read latency
//   ss_m (ones . own frag)
//   Poth x2 (partner frag)            -> ds_read covered by 5 MFMAs above
//   ss_o (ones . partner frag)
// Rv = Pown+Poth lag-1 on VALU (R13). ss = ss_m[0]+ss_o[0]: full 64-state
// sum in every lane, capture scheme identical to R13; commutative add ->
// bit-identical across the pair -> pow2 rescale consistent.
// 2048 waves = 2/SIMD: V(waveA) overlaps M(waveB); MFMA pipe dual-fed.
// Unnormalized recursion + exact pow2 octet rescale + once-per-32 flush
// (store duty split by q-parity) unchanged from R10/R13.

#define U_ 256
#define N_ 64
#define S_ 4
#define B_ 64
#define T_ 1024
#define ROWP 72
#define LN2F 0.69314718055994530942f

typedef __attribute__((ext_vector_type(8))) __bf16 bf16x8;
typedef __attribute__((ext_vector_type(4))) float floatx4;

__device__ __forceinline__ int sig(int jt, int m) {
    return 32 * (jt >> 1) + 4 * (jt & 1) + 8 * (m >> 2) + (m & 3);
}

__launch_bounds__(512, 2)
__global__ void hmm_fwd_kernel(const float* __restrict__ xg,     // [B][T][S]
                               const float* __restrict__ trans,  // [U][N][N]
                               const float* __restrict__ emis,   // [U][N][S]
                               const float* __restrict__ initk,  // [U][N]
                               float* __restrict__ out)          // [B][T][U]
{
    __shared__ __bf16 AT[N_ * ROWP];
    __shared__ float BemS[N_][S_];
    __shared__ float IS[N_];
    __align__(16) __shared__ __bf16 XFR[2][8][64][8];   // [buf][wave][lane][frag]

    const int bid = blockIdx.x;
    const int u = ((bid & 7) << 5) | (bid >> 3);   // XCD-aware u swizzle
    const int tid = threadIdx.x;
    const int lane = tid & 63;
    const int w = tid >> 6;          // 0..7
    const int p = w & 1;             // j-half parity
    const int gidx = w >> 1;         // batch group 0..3
    const int q = lane >> 4;
    const int l = lane & 15;

    // ---------------- prologue: softmaxes (one-time) ----------------
    if (tid < 64) {
        const float* rowp = trans + (u * N_ + tid) * N_;
        float v[N_];
        #pragma unroll
        for (int k = 0; k < 16; ++k) {
            floatx4 t4 = *(const floatx4*)(rowp + 4 * k);
            v[4*k] = t4.x; v[4*k+1] = t4.y; v[4*k+2] = t4.z; v[4*k+3] = t4.w;
        }
        float m = v[0];
        #pragma unroll
        for (int j = 1; j < N_; ++j) m = fmaxf(m, v[j]);
        float s = 0.f;
        #pragma unroll
        for (int j = 0; j < N_; ++j) { v[j] = __expf(v[j] - m); s += v[j]; }
        float inv = 1.0f / s;
        #pragma unroll
        for (int j = 0; j < N_; ++j) AT[j * ROWP + tid] = (__bf16)(v[j] * inv);
    } else if (tid < 128) {
        int n = tid - 64;
        floatx4 e4 = *(const floatx4*)(emis + (u * N_ + n) * S_);
        float m = fmaxf(fmaxf(e4.x, e4.y), fmaxf(e4.z, e4.w));
        float a = __expf(e4.x - m), b2 = __expf(e4.y - m);
        float c = __expf(e4.z - m), d = __expf(e4.w - m);
        float inv = 1.0f / (a + b2 + c + d);
        BemS[n][0] = a*inv; BemS[n][1] = b2*inv; BemS[n][2] = c*inv; BemS[n][3] = d*inv;
    } else if (tid < 192) {
        int j = tid - 128;
        float v = initk[u * N_ + j];
        float m = v;
        #pragma unroll
        for (int s = 1; s < 64; s <<= 1) m = fmaxf(m, __shfl_xor(m, s, 64));
        float e = __expf(v - m);
        float ssum = e;
        #pragma unroll
        for (int s = 1; s < 64; s <<= 1) ssum += __shfl_xor(ssum, s, 64);
        IS[j] = e / ssum;
    }
    __syncthreads();

    // ------------- persistent register state (2 owned tiles) -------------
    bf16x8 afrag[2][2];
    #pragma unroll
    for (int jtl = 0; jtl < 2; ++jtl)
        #pragma unroll
        for (int kt = 0; kt < 2; ++kt)
            afrag[jtl][kt] = *(const bf16x8*)&AT[sig(2*p + jtl, l) * ROWP + 32*kt + 8*q];

    bf16x8 afragE[2];
    #pragma unroll
    for (int jtl = 0; jtl < 2; ++jtl) {
        #pragma unroll
        for (int pp = 0; pp < 8; ++pp) afragE[jtl][pp] = (__bf16)0.f;
        if (q == 0) {
            #pragma unroll
            for (int c = 0; c < 4; ++c)
                afragE[jtl][c] = (__bf16)BemS[sig(2*p + jtl, l)][c];
        }
    }

    bf16x8 onesf;
    #pragma unroll
    for (int pp = 0; pp < 8; ++pp) onesf[pp] = (__bf16)1.0f;

    // Rv(t) = Pown + Poth, combined lag-1 on VALU
    floatx4 Pown[2], Poth[2];
    #pragma unroll
    for (int jtl = 0; jtl < 2; ++jtl)
        #pragma unroll
        for (int r = 0; r < 4; ++r) {
            Pown[jtl][r] = IS[sig(2*p + jtl, 4*q + r)];
            Poth[jtl][r] = 0.f;
        }

    __asm__ volatile("" ::: "memory");   // pin LDS-sourced state in VGPRs

    const int b = 16*gidx + l;
    const float* xin = xg + b * (T_ * S_);
    float* llout = out + (size_t)b * T_ * U_ + u;

    const floatx4 z = {0.f, 0.f, 0.f, 0.f};
    floatx4 Ev[2];
    floatx4 ssm = z, sso = z;            // prev step's ones-MFMA half-sums

    bf16x8 be;
    #pragma unroll
    for (int pp = 0; pp < 8; ++pp) be[pp] = (__bf16)0.f;   // hi half stays 0

    // ---------------- pipeline fill ----------------
    {
        floatx4 x0 = *(const floatx4*)xin;
        be[0] = (__bf16)x0.x; be[1] = (__bf16)x0.y;
        be[2] = (__bf16)x0.z; be[3] = (__bf16)x0.w;
        #pragma unroll
        for (int jtl = 0; jtl < 2; ++jtl)
            Ev[jtl] = __builtin_amdgcn_mfma_f32_16x16x32_bf16(afragE[jtl], be, z, 0, 0, 0);
    }
    floatx4 xvA[4], xvB[4];
    #pragma unroll
    for (int i = 0; i < 4; ++i)
        xvA[i] = *(const floatx4*)(xin + (1 + i) * S_);   // x_1..x_4 raw

    float hist[8];
    float ssf = 1.0f;
    float fcur = 1.0f;                   // pow2 rescale, applied at slot 0
    float Cacc = 0.f;
    float offacc = 0.f, sumk = 0.f;

    __bf16* xfr_me = &XFR[0][w][lane][0];
    const __bf16* xfr_pa = &XFR[0][w ^ 1][lane][0];
    const int bufoff = 8 * 64 * 8;       // bf16 elems per buffer

    // one HMM step. xr = raw x_{t+1}. buf alternates per step (literal).
    auto step = [&](const floatx4& xr, int slot, bool own, bool ownP, float fsc, int buf) {
        // ---------- V phase ----------
        // capture previous step's ss (oldest MFMA results first)
        {
            float ssp = ssm[0] + sso[0];
            if (slot == 0) {
                hist[7] = ownP ? ssp : hist[7];
            } else {
                hist[slot - 1] = own ? ssp : hist[slot - 1];
                if (slot == 6) ssf = ssp;   // slot-5 ss, 2 steps of slack
            }
        }

        floatx4 Rv[2];
        #pragma unroll
        for (int jtl = 0; jtl < 2; ++jtl) Rv[jtl] = Pown[jtl] + Poth[jtl];

        floatx4 gv[2];
        #pragma unroll
        for (int jtl = 0; jtl < 2; ++jtl) gv[jtl] = (Ev[jtl] * Rv[jtl]) * fsc;

        // pack my half-fragment (K-half p): identical code both parities
        bf16x8 bfm;
        #pragma unroll
        for (int pp = 0; pp < 4; ++pp) {
            bfm[pp]     = (__bf16)gv[0][pp];
            bfm[4 + pp] = (__bf16)gv[1][pp];
        }

        // be: only low 4 elems change (hi half constant zero)
        be[0] = (__bf16)xr.x; be[1] = (__bf16)xr.y;
        be[2] = (__bf16)xr.z; be[3] = (__bf16)xr.w;

        // ---------- exchange ----------
        *(bf16x8*)(xfr_me + buf * bufoff) = bfm;
        __asm__ volatile("s_waitcnt lgkmcnt(0)\n\ts_barrier" ::: "memory");
        bf16x8 bfo = *(const bf16x8*)(xfr_pa + buf * bufoff);

        // ---------- M phase: 8 MFMAs ----------
        // bfo-independent first (covers the ds_read latency)
        #pragma unroll
        for (int jtl = 0; jtl < 2; ++jtl)
            Ev[jtl] = __builtin_amdgcn_mfma_f32_16x16x32_bf16(afragE[jtl], be, z, 0, 0, 0);
        #pragma unroll
        for (int jtl = 0; jtl < 2; ++jtl)
            Pown[jtl] = __builtin_amdgcn_mfma_f32_16x16x32_bf16(afrag[jtl][p], bfm, z, 0, 0, 0);
        ssm = __builtin_amdgcn_mfma_f32_16x16x32_bf16(onesf, bfm, z, 0, 0, 0);
        #pragma unroll
        for (int jtl = 0; jtl < 2; ++jtl)
            Poth[jtl] = __builtin_amdgcn_mfma_f32_16x16x32_bf16(afrag[jtl][1 - p], bfo, z, 0, 0, 0);
        sso = __builtin_amdgcn_mfma_f32_16x16x32_bf16(onesf, bfo, z, 0, 0, 0);
    };

    // ---------------- T-loop: one octet per iteration ----------------
    #pragma unroll 1
    for (int tb = 0; tb < T_; tb += 8) {
        const int oct = (tb >> 3) & 3;
        const bool own  = (q == oct);
        const bool ownP = (q == ((oct + 3) & 3));

        #pragma unroll
        for (int i = 0; i < 4; ++i) {
            int ti = tb + 5 + i; ti = (ti < T_) ? ti : T_ - 1;
            xvB[i] = *(const floatx4*)(xin + ti * S_);
        }

        step(xvA[0], 0, own, ownP, fcur, 0);
        step(xvA[1], 1, own, ownP, 1.0f, 1);
        step(xvA[2], 2, own, ownP, 1.0f, 0);
        step(xvA[3], 3, own, ownP, 1.0f, 1);

        #pragma unroll
        for (int i = 0; i < 4; ++i) {
            int ti = tb + 9 + i; ti = (ti < T_) ? ti : T_ - 1;
            xvA[i] = *(const floatx4*)(xin + ti * S_);
        }

        step(xvB[0], 4, own, ownP, 1.0f, 0);
        step(xvB[1], 5, own, ownP, 1.0f, 1);
        step(xvB[2], 6, own, ownP, 1.0f, 0);
        step(xvB[3], 7, own, ownP, 1.0f, 1);

        if (oct == 3) {   // pre-flush tail capture of slot 7 (once per 32)
            float ssp = ssm[0] + sso[0];
            hist[7] = own ? ssp : hist[7];
        }

        // octet boundary: derive next pow2 rescale from ssraw_{slot5}.
        // Both waves compute bit-identical ssf -> identical fcur.
        {
            unsigned eb = (__float_as_uint(ssf) >> 23) & 255u;
            fcur = __uint_as_float((254u - eb) << 23);
            float kf = (float)((int)eb - 127);
            offacc += (q > oct) ? kf : 0.f;   // octets before lane q's octet
            sumk   += kf;
        }

        // ---------------- flush: ll_t = log(ssraw_t) + correction -------
        // store duty split by q-parity across the wave pair
        if (oct == 3) {
            float base = Cacc + LN2F * offacc;
            if ((q & 1) == p) {
                float* fp = llout + (size_t)(tb - 24 + 8 * q) * U_;
                #pragma unroll
                for (int k = 0; k < 8; ++k)
                    fp[(size_t)k * U_] = __logf(hist[k]) + base;
            }
            Cacc += LN2F * sumk;
            offacc = 0.f; sumk = 0.f;
        }
    }
}

extern "C" void kernel_launch(void* const* d_in, const int* in_sizes, int n_in,
                              void* d_out, int out_size, void* d_ws, size_t ws_size,
                              hipStream_t stream) {
    const float* xg    = (const float*)d_in[0];
    const float* trans = (const float*)d_in[1];
    const float* emis  = (const float*)d_in[2];
    const float* initk = (const float*)d_in[3];
    float* out = (float*)d_out;
    hipLaunchKernelGGL(hmm_fwd_kernel, dim3(U_), dim3(512), 0, stream,
                       xg, trans, emis, initk, out);
}